// Round 1
// baseline (584.389 us; speedup 1.0000x reference)
//
#include <hip/hip_runtime.h>
#include <hip/hip_bf16.h>

// ---------- types ----------
typedef __attribute__((ext_vector_type(8))) __bf16 bf16x8;
typedef __attribute__((ext_vector_type(2))) __bf16 bf16x2;
typedef __attribute__((ext_vector_type(4))) float f32x4;

#define T_SEQ 2048
#define C_DIM 2048
#define QKV_DIM 3072
#define NKV 4
#define HD 128

#define AS1 __attribute__((address_space(1)))
#define AS3 __attribute__((address_space(3)))

__device__ __forceinline__ unsigned short f2bf(float x) {
    __hip_bfloat16 h = __float2bfloat16(x);
    return __builtin_bit_cast(unsigned short, h);
}
__device__ __forceinline__ float bf2f(unsigned short u) {
    unsigned int i = ((unsigned int)u) << 16;
    return __builtin_bit_cast(float, i);
}
__device__ __forceinline__ unsigned int pkbf(float lo, float hi) {
#if __has_builtin(__builtin_amdgcn_cvt_pk_bf16_f32)
    bf16x2 r = __builtin_amdgcn_cvt_pk_bf16_f32(lo, hi);
    return __builtin_bit_cast(unsigned int, r);
#else
    return ((unsigned int)f2bf(hi) << 16) | (unsigned int)f2bf(lo);
#endif
}
__device__ __forceinline__ f32x4 mfma16(bf16x8 a, bf16x8 b, f32x4 c) {
    return __builtin_amdgcn_mfma_f32_16x16x32_bf16(a, b, c, 0, 0, 0);
}
__device__ __forceinline__ void gload_lds16(const void* g, void* l) {
    __builtin_amdgcn_global_load_lds((const AS1 unsigned int*)g,
                                     (AS3 unsigned int*)l, 16, 0, 0);
}

// ---------- elementwise cast x -> bf16 ----------
__global__ __launch_bounds__(256) void cast_f32_to_bf16(
        const float* __restrict__ in, unsigned short* __restrict__ out, int n4) {
    int i = blockIdx.x * 256 + threadIdx.x;
    if (i >= n4) return;
    float4 v = ((const float4*)in)[i];
    uint2 o;
    o.x = pkbf(v.x, v.y);
    o.y = pkbf(v.z, v.w);
    ((uint2*)out)[i] = o;
}

// ---------- cast+transpose fp32 [rows][cols] -> bf16 [cols][rows] ----------
__global__ __launch_bounds__(256) void transpose_cast_f32_bf16(
        const float* __restrict__ in, unsigned short* __restrict__ out,
        int rows, int cols) {
    __shared__ float tile[32][33];
    int c0 = blockIdx.x * 32, r0 = blockIdx.y * 32;
    int tx = threadIdx.x, ty = threadIdx.y;
    #pragma unroll
    for (int i = 0; i < 4; i++)
        tile[ty + 8 * i][tx] = in[(size_t)(r0 + ty + 8 * i) * cols + c0 + tx];
    __syncthreads();
    #pragma unroll
    for (int i = 0; i < 4; i++)
        out[(size_t)(c0 + ty + 8 * i) * rows + r0 + tx] = f2bf(tile[tx][ty + 8 * i]);
}

// ---------- transpose V cols of qkv -> tiled vt[b][kv][t/32][d 0..127][t%32] ----------
__global__ __launch_bounds__(256) void transpose_v(
        const unsigned short* __restrict__ qkv, unsigned short* __restrict__ vt) {
    __shared__ unsigned short tile[32][33];
    int c0 = blockIdx.x * 32;   // d-col 0..511
    int r0 = blockIdx.y * 32;   // row (b*T+t) 0..4095
    int tx = threadIdx.x, ty = threadIdx.y;
    #pragma unroll
    for (int i = 0; i < 4; i++)
        tile[ty + 8 * i][tx] =
            qkv[(size_t)(r0 + ty + 8 * i) * QKV_DIM + 2560 + c0 + tx];
    __syncthreads();
    #pragma unroll
    for (int i = 0; i < 4; i++) {
        int dcol = c0 + ty + 8 * i;
        int kv = dcol >> 7, d = dcol & 127;
        int r = r0 + tx;
        int b = r >> 11, t = r & (T_SEQ - 1);
        vt[(size_t)((b * NKV + kv) * 64 + (t >> 5)) * 4096 + d * 32 + (t & 31)] =
            tile[tx][ty + 8 * i];
    }
}

// ---------- YaRN cos/sin table ----------
__global__ __launch_bounds__(256) void yarn_tab_kernel(float2* __restrict__ tab) {
    int idx = blockIdx.x * 256 + threadIdx.x;   // t*64 + i
    int t = idx >> 6, i = idx & 63;
    float inv = 0.25f * exp2f(-(float)i * (13.287712379549449f / 64.0f));
    float ang = (float)t * inv;
    float s, c;
    __sincosf(ang, &s, &c);
    tab[idx] = make_float2(c, s);
}

// ---------- RoPE via table ----------
__global__ __launch_bounds__(256) void rope_kernel(
        unsigned short* __restrict__ qkv, const float2* __restrict__ tab) {
    int row = blockIdx.x;
    int t = row & (T_SEQ - 1);
    const float2* tb = tab + t * 64;
    for (int p = threadIdx.x; p < 1280; p += 256) {
        int head = p >> 6, i = p & 63;
        float2 cs = tb[i];
        size_t idx = (size_t)row * QKV_DIM + head * 128 + 2 * i;
        unsigned int u = *(const unsigned int*)(qkv + idx);
        float e = bf2f((unsigned short)(u & 0xffff));
        float o = bf2f((unsigned short)(u >> 16));
        *(unsigned int*)(qkv + idx) = pkbf(e * cs.x - o * cs.y, o * cs.x + e * cs.y);
    }
}

// ---------- GEMM (m97 structure): C[M,N] = A[M,K] @ Bt[N,K]^T ----------
template <int OUT_BF16>
__global__ __launch_bounds__(256) void gemm_bt(
        const unsigned short* __restrict__ A, const unsigned short* __restrict__ Bt,
        void* __restrict__ Cout, int M, int N, int K) {
    __shared__ __align__(16) unsigned short As[128 * 32];
    __shared__ __align__(16) unsigned short Bs[128 * 32];
    int tid = threadIdx.x;
    int m0 = blockIdx.y * 128, n0 = blockIdx.x * 128;
    int wave = tid >> 6, lane = tid & 63;
    int wm = (wave & 1) * 64, wn = (wave >> 1) * 64;
    int l15 = lane & 15, quad = lane >> 4;
    int lrow = lane >> 2, lcol = (lane & 3) * 8;

    f32x4 zf = {0.f, 0.f, 0.f, 0.f};
    f32x4 acc[4][4];
    #pragma unroll
    for (int i = 0; i < 4; i++)
        #pragma unroll
        for (int j = 0; j < 4; j++) acc[i][j] = zf;

    int ca = wave * 2;
    const unsigned short* gA = A + (size_t)(m0 + ca * 16 + lrow) * K + lcol;
    const unsigned short* gB = Bt + (size_t)(n0 + ca * 16 + lrow) * K + lcol;

    for (int k0 = 0; k0 < K; k0 += 32) {
        gload_lds16(gA + k0, &As[ca * 512]);
        gload_lds16(gA + k0 + 16 * (size_t)K, &As[ca * 512 + 512]);
        gload_lds16(gB + k0, &Bs[ca * 512]);
        gload_lds16(gB + k0 + 16 * (size_t)K, &Bs[ca * 512 + 512]);
        __syncthreads();
        bf16x8 af[4], bfr[4];
        #pragma unroll
        for (int i = 0; i < 4; i++)
            af[i] = *(const bf16x8*)&As[(wm + i * 16 + l15) * 32 + quad * 8];
        #pragma unroll
        for (int i = 0; i < 4; i++)
            bfr[i] = *(const bf16x8*)&Bs[(wn + i * 16 + l15) * 32 + quad * 8];
        #pragma unroll
        for (int mi = 0; mi < 4; mi++)
            #pragma unroll
            for (int ni = 0; ni < 4; ni++)
                acc[mi][ni] = mfma16(af[mi], bfr[ni], acc[mi][ni]);
        __syncthreads();
    }
    #pragma unroll
    for (int mi = 0; mi < 4; mi++)
        #pragma unroll
        for (int ni = 0; ni < 4; ni++) {
            int row = m0 + wm + mi * 16 + quad * 4;
            int col = n0 + wn + ni * 16 + l15;
            #pragma unroll
            for (int r = 0; r < 4; r++) {
                float v = acc[mi][ni][r];
                if (OUT_BF16)
                    ((unsigned short*)Cout)[(size_t)(row + r) * N + col] = f2bf(v);
                else
                    ((float*)Cout)[(size_t)(row + r) * N + col] = v;
            }
        }
}

// ---------- flash attention: 1 wave per q-tile, software-pipelined ----------
__device__ __forceinline__ void attn_one(
        const unsigned short* __restrict__ qkv, const unsigned short* __restrict__ vt,
        unsigned short* __restrict__ attn_out, unsigned int* __restrict__ pT,
        int b, int h, int qt, int lane) {
    int l15 = lane & 15, quad = lane >> 4;
    int kv = h >> 2;
    f32x4 zf = {0.f, 0.f, 0.f, 0.f};

    // Q B-frag: Q[qrow=l15][k=c*32+quad*8+j]
    const unsigned short* qp =
        qkv + (size_t)(b * T_SEQ + qt * 16 + l15) * QKV_DIM + h * HD + quad * 8;
    bf16x8 aq[4];
    #pragma unroll
    for (int c = 0; c < 4; c++) aq[c] = *(const bf16x8*)(qp + c * 32);

    const unsigned short* kbase = qkv + (size_t)b * T_SEQ * QKV_DIM + 2048 + kv * HD;
    const unsigned short* vbase = vt + (size_t)(b * NKV + kv) * 64 * 4096;
    const unsigned short* pk0 = kbase + (size_t)l15 * QKV_DIM + quad * 8;
    const unsigned short* pk1 = pk0 + (size_t)16 * QKV_DIM;
    const unsigned short* pv0 = vbase + l15 * 32 + quad * 8;
    const unsigned short* pv1 = pv0 + 2048;

    f32x4 oacc[8];
    #pragma unroll
    for (int d = 0; d < 8; d++) oacc[d] = zf;
    float lsum = 0.f;

    int qglob = qt * 16 + l15;
    int n = (qt >> 1) + 1;   // number of 32-key tiles

    const float K1 = 0.0051006972f;         // invsqrt(128)*(2/50)*log2(e)
    const float K2 = -144.26950408889634f;  // -100*log2(e)
    const float K3 = 72.13475204444817f;    // 50*log2(e)

    bf16x8 KA[8], KB[8];

    auto loadK = [&](bf16x8* K, int t) {
        const unsigned short* a = pk0 + (size_t)t * 32 * QKV_DIM;
        const unsigned short* b_ = pk1 + (size_t)t * 32 * QKV_DIM;
        #pragma unroll
        for (int c = 0; c < 4; c++) {
            K[c] = *(const bf16x8*)(a + c * 32);
            K[4 + c] = *(const bf16x8*)(b_ + c * 32);
        }
    };

    auto step = [&](const bf16x8* K, unsigned int* buf, bool masked, int t,
                    bf16x8* Kpre, int tpre, bool do_pre) {
        // V loads first (oldest vmem of this tile)
        const unsigned short* v0 = pv0 + (size_t)t * 4096;
        const unsigned short* v1 = pv1 + (size_t)t * 4096;
        bf16x8 Vv[8];
        #pragma unroll
        for (int dd = 0; dd < 4; dd++) {
            Vv[dd] = *(const bf16x8*)(v0 + dd * 512);
            Vv[4 + dd] = *(const bf16x8*)(v1 + dd * 512);
        }
        // prefetch next K (stays in flight across PV's vmcnt wait)
        if (do_pre) loadK(Kpre, tpre);
        // S^T = K.Q^T
        f32x4 s0 = zf, s1 = zf;
        #pragma unroll
        for (int c = 0; c < 4; c++) {
            s0 = mfma16(K[c], aq[c], s0);
            s1 = mfma16(K[4 + c], aq[c], s1);
        }
        float p0[4], p1[4];
        int kb = t * 32 + quad * 4;
        #pragma unroll
        for (int r = 0; r < 4; r++) {
            float e0 = exp2f(s0[r] * K1);
            float e1 = exp2f(s1[r] * K1);
            float q0 = exp2f(fmaf(K2, __builtin_amdgcn_rcpf(e0 + 1.f), K3));
            float q1 = exp2f(fmaf(K2, __builtin_amdgcn_rcpf(e1 + 1.f), K3));
            if (masked) {
                q0 = (kb + r <= qglob) ? q0 : 0.f;
                q1 = (kb + 16 + r <= qglob) ? q1 : 0.f;
            }
            p0[r] = q0; p1[r] = q1;
            lsum += q0 + q1;
        }
        // P^T transpose via LDS (single wave, in-order)
        unsigned int d0 = pkbf(p0[0], p0[1]), d1 = pkbf(p0[2], p0[3]);
        unsigned int d2 = pkbf(p1[0], p1[1]), d3 = pkbf(p1[2], p1[3]);
        unsigned int* wp = buf + l15 * 20 + quad * 2;
        *(uint2*)wp = make_uint2(d0, d1);
        *(uint2*)(wp + 8) = make_uint2(d2, d3);
        __asm__ volatile("s_waitcnt lgkmcnt(0)" ::: "memory");
        bf16x8 bp = *(const bf16x8*)(buf + l15 * 20 + quad * 4);
        // O^T += V^T . P^T
        #pragma unroll
        for (int dd = 0; dd < 8; dd++) oacc[dd] = mfma16(Vv[dd], bp, oacc[dd]);
    };

    loadK(KA, 0);
    int t = 0;
    while (true) {
        bool last = (t == n - 1);
        step(KA, pT, last, t, KB, t + 1, !last);
        if (last) break;
        t++;
        last = (t == n - 1);
        step(KB, pT + 320, last, t, KA, t + 1, !last);
        if (last) break;
        t++;
    }

    float l = lsum;
    l += __shfl_xor(l, 16);
    l += __shfl_xor(l, 32);
    float rl = __builtin_amdgcn_rcpf(l);
    unsigned short* op = attn_out +
        (size_t)(b * T_SEQ + qt * 16 + l15) * C_DIM + h * HD + quad * 4;
    #pragma unroll
    for (int dd = 0; dd < 8; dd++) {
        unsigned int u0 = pkbf(oacc[dd][0] * rl, oacc[dd][1] * rl);
        unsigned int u1 = pkbf(oacc[dd][2] * rl, oacc[dd][3] * rl);
        *(uint2*)(op + dd * 16) = make_uint2(u0, u1);
    }
}

// One q-tile per block (4096 blocks = 16 waves/CU = 4 waves/SIMD, double the
// previous occupancy). Load balance via dispatch order: longest tiles
// (qt=127, 65 key-steps) launch first, 1-step tiles fill the scheduling tail.
__global__ __launch_bounds__(64, 4) void attn_kernel(
        const unsigned short* __restrict__ qkv, const unsigned short* __restrict__ vt,
        unsigned short* __restrict__ attn_out) {
    __shared__ __align__(16) unsigned int pT[2 * 320];
    int bid = blockIdx.x;
    int qt = 127 - (bid >> 5);      // descending work
    int bh = bid & 31;
    int b = bh >> 4, h = bh & 15;
    attn_one(qkv, vt, attn_out, pT, b, h, qt, threadIdx.x);
}

extern "C" void kernel_launch(void* const* d_in, const int* in_sizes, int n_in,
                              void* d_out, int out_size, void* d_ws, size_t ws_size,
                              hipStream_t stream) {
    (void)in_sizes; (void)n_in; (void)out_size; (void)ws_size;
    const float* x = (const float*)d_in[0];
    const float* w_qkv = (const float*)d_in[1];
    const float* w_o = (const float*)d_in[2];
    char* ws = (char*)d_ws;

    unsigned short* xbf   = (unsigned short*)(ws);                       // 16 MB
    unsigned short* wqkvT = (unsigned short*)(ws + 16777216);            // 12 MB
    unsigned short* woT   = (unsigned short*)(ws + 29360128);            //  8 MB
    unsigned short* qkv   = (unsigned short*)(ws + 37748736);            // 24 MB
    unsigned short* vt    = (unsigned short*)(ws + 62914560);            //  4 MB -> 64 MB
    float2*         tab   = (float2*)(ws + 62914560);  // overlaps vt: dead before transpose_v
    unsigned short* attn  = xbf;  // xbf dead after gemm1

    cast_f32_to_bf16<<<8192, 256, 0, stream>>>(x, xbf, 2097152);
    transpose_cast_f32_bf16<<<dim3(96, 64), dim3(32, 8), 0, stream>>>(w_qkv, wqkvT, 2048, 3072);
    transpose_cast_f32_bf16<<<dim3(64, 64), dim3(32, 8), 0, stream>>>(w_o, woT, 2048, 2048);
    yarn_tab_kernel<<<512, 256, 0, stream>>>(tab);
    gemm_bt<1><<<dim3(24, 32), 256, 0, stream>>>(xbf, wqkvT, qkv, 4096, 3072, 2048);
    rope_kernel<<<4096, 256, 0, stream>>>(qkv, tab);
    transpose_v<<<dim3(16, 128), dim3(32, 8), 0, stream>>>(qkv, vt);
    attn_kernel<<<4096, 64, 0, stream>>>(qkv, vt, attn);
    gemm_bt<0><<<dim3(16, 32), 256, 0, stream>>>(attn, woT, d_out, 4096, 2048, 2048);
}

// Round 2
// 430.580 us; speedup vs baseline: 1.3572x; 1.3572x over previous
//
#include <hip/hip_runtime.h>
#include <hip/hip_bf16.h>

// ---------- types ----------
typedef __attribute__((ext_vector_type(8))) __bf16 bf16x8;
typedef __attribute__((ext_vector_type(2))) __bf16 bf16x2;
typedef __attribute__((ext_vector_type(4))) float f32x4;

#define T_SEQ 2048
#define C_DIM 2048
#define QKV_DIM 3072
#define NKV 4
#define HD 128

#define AS1 __attribute__((address_space(1)))
#define AS3 __attribute__((address_space(3)))

__device__ __forceinline__ unsigned short f2bf(float x) {
    __hip_bfloat16 h = __float2bfloat16(x);
    return __builtin_bit_cast(unsigned short, h);
}
__device__ __forceinline__ float bf2f(unsigned short u) {
    unsigned int i = ((unsigned int)u) << 16;
    return __builtin_bit_cast(float, i);
}
__device__ __forceinline__ unsigned int pkbf(float lo, float hi) {
#if __has_builtin(__builtin_amdgcn_cvt_pk_bf16_f32)
    bf16x2 r = __builtin_amdgcn_cvt_pk_bf16_f32(lo, hi);
    return __builtin_bit_cast(unsigned int, r);
#else
    return ((unsigned int)f2bf(hi) << 16) | (unsigned int)f2bf(lo);
#endif
}
__device__ __forceinline__ f32x4 mfma16(bf16x8 a, bf16x8 b, f32x4 c) {
    return __builtin_amdgcn_mfma_f32_16x16x32_bf16(a, b, c, 0, 0, 0);
}
__device__ __forceinline__ void gload_lds16(const void* g, void* l) {
    __builtin_amdgcn_global_load_lds((const AS1 unsigned int*)g,
                                     (AS3 unsigned int*)l, 16, 0, 0);
}

// ---------- elementwise cast x -> bf16 ----------
__global__ __launch_bounds__(256) void cast_f32_to_bf16(
        const float* __restrict__ in, unsigned short* __restrict__ out, int n4) {
    int i = blockIdx.x * 256 + threadIdx.x;
    if (i >= n4) return;
    float4 v = ((const float4*)in)[i];
    uint2 o;
    o.x = pkbf(v.x, v.y);
    o.y = pkbf(v.z, v.w);
    ((uint2*)out)[i] = o;
}

// ---------- cast+transpose fp32 [rows][cols] -> bf16 [cols][rows] ----------
__global__ __launch_bounds__(256) void transpose_cast_f32_bf16(
        const float* __restrict__ in, unsigned short* __restrict__ out,
        int rows, int cols) {
    __shared__ float tile[32][33];
    int c0 = blockIdx.x * 32, r0 = blockIdx.y * 32;
    int tx = threadIdx.x, ty = threadIdx.y;
    #pragma unroll
    for (int i = 0; i < 4; i++)
        tile[ty + 8 * i][tx] = in[(size_t)(r0 + ty + 8 * i) * cols + c0 + tx];
    __syncthreads();
    #pragma unroll
    for (int i = 0; i < 4; i++)
        out[(size_t)(c0 + ty + 8 * i) * rows + r0 + tx] = f2bf(tile[tx][ty + 8 * i]);
}

// ---------- transpose V cols of qkv -> tiled vt[b][kv][t/32][d 0..127][t%32] ----------
__global__ __launch_bounds__(256) void transpose_v(
        const unsigned short* __restrict__ qkv, unsigned short* __restrict__ vt) {
    __shared__ unsigned short tile[32][33];
    int c0 = blockIdx.x * 32;   // d-col 0..511
    int r0 = blockIdx.y * 32;   // row (b*T+t) 0..4095
    int tx = threadIdx.x, ty = threadIdx.y;
    #pragma unroll
    for (int i = 0; i < 4; i++)
        tile[ty + 8 * i][tx] =
            qkv[(size_t)(r0 + ty + 8 * i) * QKV_DIM + 2560 + c0 + tx];
    __syncthreads();
    #pragma unroll
    for (int i = 0; i < 4; i++) {
        int dcol = c0 + ty + 8 * i;
        int kv = dcol >> 7, d = dcol & 127;
        int r = r0 + tx;
        int b = r >> 11, t = r & (T_SEQ - 1);
        vt[(size_t)((b * NKV + kv) * 64 + (t >> 5)) * 4096 + d * 32 + (t & 31)] =
            tile[tx][ty + 8 * i];
    }
}

// ---------- YaRN cos/sin table ----------
__global__ __launch_bounds__(256) void yarn_tab_kernel(float2* __restrict__ tab) {
    int idx = blockIdx.x * 256 + threadIdx.x;   // t*64 + i
    int t = idx >> 6, i = idx & 63;
    float inv = 0.25f * exp2f(-(float)i * (13.287712379549449f / 64.0f));
    float ang = (float)t * inv;
    float s, c;
    __sincosf(ang, &s, &c);
    tab[idx] = make_float2(c, s);
}

// ---------- RoPE via table ----------
__global__ __launch_bounds__(256) void rope_kernel(
        unsigned short* __restrict__ qkv, const float2* __restrict__ tab) {
    int row = blockIdx.x;
    int t = row & (T_SEQ - 1);
    const float2* tb = tab + t * 64;
    for (int p = threadIdx.x; p < 1280; p += 256) {
        int head = p >> 6, i = p & 63;
        float2 cs = tb[i];
        size_t idx = (size_t)row * QKV_DIM + head * 128 + 2 * i;
        unsigned int u = *(const unsigned int*)(qkv + idx);
        float e = bf2f((unsigned short)(u & 0xffff));
        float o = bf2f((unsigned short)(u >> 16));
        *(unsigned int*)(qkv + idx) = pkbf(e * cs.x - o * cs.y, o * cs.x + e * cs.y);
    }
}

// ---------- GEMM (m97 structure): C[M,N] = A[M,K] @ Bt[N,K]^T ----------
template <int OUT_BF16>
__global__ __launch_bounds__(256) void gemm_bt(
        const unsigned short* __restrict__ A, const unsigned short* __restrict__ Bt,
        void* __restrict__ Cout, int M, int N, int K) {
    __shared__ __align__(16) unsigned short As[128 * 32];
    __shared__ __align__(16) unsigned short Bs[128 * 32];
    int tid = threadIdx.x;
    int m0 = blockIdx.y * 128, n0 = blockIdx.x * 128;
    int wave = tid >> 6, lane = tid & 63;
    int wm = (wave & 1) * 64, wn = (wave >> 1) * 64;
    int l15 = lane & 15, quad = lane >> 4;
    int lrow = lane >> 2, lcol = (lane & 3) * 8;

    f32x4 zf = {0.f, 0.f, 0.f, 0.f};
    f32x4 acc[4][4];
    #pragma unroll
    for (int i = 0; i < 4; i++)
        #pragma unroll
        for (int j = 0; j < 4; j++) acc[i][j] = zf;

    int ca = wave * 2;
    const unsigned short* gA = A + (size_t)(m0 + ca * 16 + lrow) * K + lcol;
    const unsigned short* gB = Bt + (size_t)(n0 + ca * 16 + lrow) * K + lcol;

    for (int k0 = 0; k0 < K; k0 += 32) {
        gload_lds16(gA + k0, &As[ca * 512]);
        gload_lds16(gA + k0 + 16 * (size_t)K, &As[ca * 512 + 512]);
        gload_lds16(gB + k0, &Bs[ca * 512]);
        gload_lds16(gB + k0 + 16 * (size_t)K, &Bs[ca * 512 + 512]);
        __syncthreads();
        bf16x8 af[4], bfr[4];
        #pragma unroll
        for (int i = 0; i < 4; i++)
            af[i] = *(const bf16x8*)&As[(wm + i * 16 + l15) * 32 + quad * 8];
        #pragma unroll
        for (int i = 0; i < 4; i++)
            bfr[i] = *(const bf16x8*)&Bs[(wn + i * 16 + l15) * 32 + quad * 8];
        #pragma unroll
        for (int mi = 0; mi < 4; mi++)
            #pragma unroll
            for (int ni = 0; ni < 4; ni++)
                acc[mi][ni] = mfma16(af[mi], bfr[ni], acc[mi][ni]);
        __syncthreads();
    }
    #pragma unroll
    for (int mi = 0; mi < 4; mi++)
        #pragma unroll
        for (int ni = 0; ni < 4; ni++) {
            int row = m0 + wm + mi * 16 + quad * 4;
            int col = n0 + wn + ni * 16 + l15;
            #pragma unroll
            for (int r = 0; r < 4; r++) {
                float v = acc[mi][ni][r];
                if (OUT_BF16)
                    ((unsigned short*)Cout)[(size_t)(row + r) * N + col] = f2bf(v);
                else
                    ((float*)Cout)[(size_t)(row + r) * N + col] = v;
            }
        }
}

// ---------- flash attention: 1 wave per q-tile, software-pipelined ----------
__device__ __forceinline__ void attn_one(
        const unsigned short* __restrict__ qkv, const unsigned short* __restrict__ vt,
        unsigned short* __restrict__ attn_out, unsigned int* __restrict__ pT,
        int b, int h, int qt, int lane) {
    int l15 = lane & 15, quad = lane >> 4;
    int kv = h >> 2;
    f32x4 zf = {0.f, 0.f, 0.f, 0.f};

    // Q B-frag: Q[qrow=l15][k=c*32+quad*8+j]
    const unsigned short* qp =
        qkv + (size_t)(b * T_SEQ + qt * 16 + l15) * QKV_DIM + h * HD + quad * 8;
    bf16x8 aq[4];
    #pragma unroll
    for (int c = 0; c < 4; c++) aq[c] = *(const bf16x8*)(qp + c * 32);

    const unsigned short* kbase = qkv + (size_t)b * T_SEQ * QKV_DIM + 2048 + kv * HD;
    const unsigned short* vbase = vt + (size_t)(b * NKV + kv) * 64 * 4096;
    const unsigned short* pk0 = kbase + (size_t)l15 * QKV_DIM + quad * 8;
    const unsigned short* pk1 = pk0 + (size_t)16 * QKV_DIM;
    const unsigned short* pv0 = vbase + l15 * 32 + quad * 8;
    const unsigned short* pv1 = pv0 + 2048;

    f32x4 oacc[8];
    #pragma unroll
    for (int d = 0; d < 8; d++) oacc[d] = zf;
    float lsum = 0.f;

    int qglob = qt * 16 + l15;
    int n = (qt >> 1) + 1;   // number of 32-key tiles

    const float K1 = 0.0051006972f;         // invsqrt(128)*(2/50)*log2(e)
    const float K2 = -144.26950408889634f;  // -100*log2(e)
    const float K3 = 72.13475204444817f;    // 50*log2(e)

    bf16x8 KA[8], KB[8];

    auto loadK = [&](bf16x8* K, int t) {
        const unsigned short* a = pk0 + (size_t)t * 32 * QKV_DIM;
        const unsigned short* b_ = pk1 + (size_t)t * 32 * QKV_DIM;
        #pragma unroll
        for (int c = 0; c < 4; c++) {
            K[c] = *(const bf16x8*)(a + c * 32);
            K[4 + c] = *(const bf16x8*)(b_ + c * 32);
        }
    };

    auto step = [&](const bf16x8* K, unsigned int* buf, bool masked, int t,
                    bf16x8* Kpre, int tpre, bool do_pre) {
        // V loads first (oldest vmem of this tile)
        const unsigned short* v0 = pv0 + (size_t)t * 4096;
        const unsigned short* v1 = pv1 + (size_t)t * 4096;
        bf16x8 Vv[8];
        #pragma unroll
        for (int dd = 0; dd < 4; dd++) {
            Vv[dd] = *(const bf16x8*)(v0 + dd * 512);
            Vv[4 + dd] = *(const bf16x8*)(v1 + dd * 512);
        }
        // prefetch next K (stays in flight across PV's vmcnt wait)
        if (do_pre) loadK(Kpre, tpre);
        // S^T = K.Q^T
        f32x4 s0 = zf, s1 = zf;
        #pragma unroll
        for (int c = 0; c < 4; c++) {
            s0 = mfma16(K[c], aq[c], s0);
            s1 = mfma16(K[4 + c], aq[c], s1);
        }
        float p0[4], p1[4];
        int kb = t * 32 + quad * 4;
        #pragma unroll
        for (int r = 0; r < 4; r++) {
            float e0 = exp2f(s0[r] * K1);
            float e1 = exp2f(s1[r] * K1);
            float q0 = exp2f(fmaf(K2, __builtin_amdgcn_rcpf(e0 + 1.f), K3));
            float q1 = exp2f(fmaf(K2, __builtin_amdgcn_rcpf(e1 + 1.f), K3));
            if (masked) {
                q0 = (kb + r <= qglob) ? q0 : 0.f;
                q1 = (kb + 16 + r <= qglob) ? q1 : 0.f;
            }
            p0[r] = q0; p1[r] = q1;
            lsum += q0 + q1;
        }
        // P^T transpose via LDS (single wave, in-order)
        unsigned int d0 = pkbf(p0[0], p0[1]), d1 = pkbf(p0[2], p0[3]);
        unsigned int d2 = pkbf(p1[0], p1[1]), d3 = pkbf(p1[2], p1[3]);
        unsigned int* wp = buf + l15 * 20 + quad * 2;
        *(uint2*)wp = make_uint2(d0, d1);
        *(uint2*)(wp + 8) = make_uint2(d2, d3);
        __asm__ volatile("s_waitcnt lgkmcnt(0)" ::: "memory");
        bf16x8 bp = *(const bf16x8*)(buf + l15 * 20 + quad * 4);
        // O^T += V^T . P^T
        #pragma unroll
        for (int dd = 0; dd < 8; dd++) oacc[dd] = mfma16(Vv[dd], bp, oacc[dd]);
    };

    loadK(KA, 0);
    int t = 0;
    while (true) {
        bool last = (t == n - 1);
        step(KA, pT, last, t, KB, t + 1, !last);
        if (last) break;
        t++;
        last = (t == n - 1);
        step(KB, pT + 320, last, t, KA, t + 1, !last);
        if (last) break;
        t++;
    }

    float l = lsum;
    l += __shfl_xor(l, 16);
    l += __shfl_xor(l, 32);
    float rl = __builtin_amdgcn_rcpf(l);
    unsigned short* op = attn_out +
        (size_t)(b * T_SEQ + qt * 16 + l15) * C_DIM + h * HD + quad * 4;
    #pragma unroll
    for (int dd = 0; dd < 8; dd++) {
        unsigned int u0 = pkbf(oacc[dd][0] * rl, oacc[dd][1] * rl);
        unsigned int u1 = pkbf(oacc[dd][2] * rl, oacc[dd][3] * rl);
        *(uint2*)(op + dd * 16) = make_uint2(u0, u1);
    }
}

// One q-tile per block (4096 blocks = 16 blocks/CU). launch_bounds kept at
// (64,2): round-0 codegen (96 VGPR <= 128) already permits 4 waves/SIMD;
// the (64,4) hint capped VGPRs at 64 and spilled to scratch (695 MB writes).
// Longest tiles (qt=127) launch first, 1-step tiles fill the tail.
__global__ __launch_bounds__(64, 2) void attn_kernel(
        const unsigned short* __restrict__ qkv, const unsigned short* __restrict__ vt,
        unsigned short* __restrict__ attn_out) {
    __shared__ __align__(16) unsigned int pT[2 * 320];
    int bid = blockIdx.x;
    int qt = 127 - (bid >> 5);      // descending work
    int bh = bid & 31;
    int b = bh >> 4, h = bh & 15;
    attn_one(qkv, vt, attn_out, pT, b, h, qt, threadIdx.x);
}

extern "C" void kernel_launch(void* const* d_in, const int* in_sizes, int n_in,
                              void* d_out, int out_size, void* d_ws, size_t ws_size,
                              hipStream_t stream) {
    (void)in_sizes; (void)n_in; (void)out_size; (void)ws_size;
    const float* x = (const float*)d_in[0];
    const float* w_qkv = (const float*)d_in[1];
    const float* w_o = (const float*)d_in[2];
    char* ws = (char*)d_ws;

    unsigned short* xbf   = (unsigned short*)(ws);                       // 16 MB
    unsigned short* wqkvT = (unsigned short*)(ws + 16777216);            // 12 MB
    unsigned short* woT   = (unsigned short*)(ws + 29360128);            //  8 MB
    unsigned short* qkv   = (unsigned short*)(ws + 37748736);            // 24 MB
    unsigned short* vt    = (unsigned short*)(ws + 62914560);            //  4 MB -> 64 MB
    float2*         tab   = (float2*)(ws + 62914560);  // overlaps vt: dead before transpose_v
    unsigned short* attn  = xbf;  // xbf dead after gemm1

    cast_f32_to_bf16<<<8192, 256, 0, stream>>>(x, xbf, 2097152);
    transpose_cast_f32_bf16<<<dim3(96, 64), dim3(32, 8), 0, stream>>>(w_qkv, wqkvT, 2048, 3072);
    transpose_cast_f32_bf16<<<dim3(64, 64), dim3(32, 8), 0, stream>>>(w_o, woT, 2048, 2048);
    yarn_tab_kernel<<<512, 256, 0, stream>>>(tab);
    gemm_bt<1><<<dim3(24, 32), 256, 0, stream>>>(xbf, wqkvT, qkv, 4096, 3072, 2048);
    rope_kernel<<<4096, 256, 0, stream>>>(qkv, tab);
    transpose_v<<<dim3(16, 128), dim3(32, 8), 0, stream>>>(qkv, vt);
    attn_kernel<<<4096, 64, 0, stream>>>(qkv, vt, attn);
    gemm_bt<0><<<dim3(16, 32), 256, 0, stream>>>(attn, woT, d_out, 4096, 2048, 2048);
}

// Round 3
// 350.585 us; speedup vs baseline: 1.6669x; 1.2282x over previous
//
#include <hip/hip_runtime.h>
#include <hip/hip_bf16.h>

// ---------- types ----------
typedef __attribute__((ext_vector_type(8))) __bf16 bf16x8;
typedef __attribute__((ext_vector_type(2))) __bf16 bf16x2;
typedef __attribute__((ext_vector_type(4))) float f32x4;

#define T_SEQ 2048
#define C_DIM 2048
#define QKV_DIM 3072
#define NKV 4
#define HD 128

#define AS1 __attribute__((address_space(1)))
#define AS3 __attribute__((address_space(3)))

__device__ __forceinline__ unsigned short f2bf(float x) {
    __hip_bfloat16 h = __float2bfloat16(x);
    return __builtin_bit_cast(unsigned short, h);
}
__device__ __forceinline__ float bf2f(unsigned short u) {
    unsigned int i = ((unsigned int)u) << 16;
    return __builtin_bit_cast(float, i);
}
__device__ __forceinline__ unsigned int pkbf(float lo, float hi) {
#if __has_builtin(__builtin_amdgcn_cvt_pk_bf16_f32)
    bf16x2 r = __builtin_amdgcn_cvt_pk_bf16_f32(lo, hi);
    return __builtin_bit_cast(unsigned int, r);
#else
    return ((unsigned int)f2bf(hi) << 16) | (unsigned int)f2bf(lo);
#endif
}
__device__ __forceinline__ f32x4 mfma16(bf16x8 a, bf16x8 b, f32x4 c) {
    return __builtin_amdgcn_mfma_f32_16x16x32_bf16(a, b, c, 0, 0, 0);
}
__device__ __forceinline__ void gload_lds16(const void* g, void* l) {
    __builtin_amdgcn_global_load_lds((const AS1 unsigned int*)g,
                                     (AS3 unsigned int*)l, 16, 0, 0);
}

// ---------- elementwise cast x -> bf16 ----------
__global__ __launch_bounds__(256) void cast_f32_to_bf16(
        const float* __restrict__ in, unsigned short* __restrict__ out, int n4) {
    int i = blockIdx.x * 256 + threadIdx.x;
    if (i >= n4) return;
    float4 v = ((const float4*)in)[i];
    uint2 o;
    o.x = pkbf(v.x, v.y);
    o.y = pkbf(v.z, v.w);
    ((uint2*)out)[i] = o;
}

// ---------- cast+transpose fp32 [rows][cols] -> bf16 [cols][rows] ----------
__global__ __launch_bounds__(256) void transpose_cast_f32_bf16(
        const float* __restrict__ in, unsigned short* __restrict__ out,
        int rows, int cols) {
    __shared__ float tile[32][33];
    int c0 = blockIdx.x * 32, r0 = blockIdx.y * 32;
    int tx = threadIdx.x, ty = threadIdx.y;
    #pragma unroll
    for (int i = 0; i < 4; i++)
        tile[ty + 8 * i][tx] = in[(size_t)(r0 + ty + 8 * i) * cols + c0 + tx];
    __syncthreads();
    #pragma unroll
    for (int i = 0; i < 4; i++)
        out[(size_t)(c0 + ty + 8 * i) * rows + r0 + tx] = f2bf(tile[tx][ty + 8 * i]);
}

// ---------- pack K (post-RoPE) into MFMA-fragment order ----------
// kpack[((b*4+kv)*128 + st)*2048 + chunk*128 + row*8 + j]
//   where st = 16-row subtile (t>>4), row = t&15, chunk = d>>3, j = d&7.
// A wave's frag load becomes addr = base + lane*8 (fully contiguous 1 KB).
__global__ __launch_bounds__(256) void pack_k(
        const unsigned short* __restrict__ qkv, unsigned short* __restrict__ kpack) {
    int sid = blockIdx.x;                 // (b*4+kv)*128 + st, 0..1023
    int tid = threadIdx.x;
    int row = tid >> 4;                   // 0..15
    int chunk = tid & 15;                 // d-chunk of 8
    int b = sid >> 9, kv = (sid >> 7) & 3, st = sid & 127;
    int t_ = st * 16 + row;
    const unsigned short* src =
        qkv + (size_t)(b * T_SEQ + t_) * QKV_DIM + 2048 + kv * HD + chunk * 8;
    unsigned short* dst = kpack + (size_t)sid * 2048 + chunk * 128 + row * 8;
    *(uint4*)dst = *(const uint4*)src;
}

// ---------- pack V^T into MFMA-fragment order ----------
// vpack[((b*4+kv)*64 + t/32)*4096 + (d>>4)*512 + ((t>>3)&3)*128 + (d&15)*8 + (t&7)]
// Frag load for Vv[dd] (rows d = 16*dd + l15, cols kv = quad*8+j):
//   addr = base + t32*4096 + dd*512 + lane*8 (contiguous 1 KB).
__global__ __launch_bounds__(256) void pack_v(
        const unsigned short* __restrict__ qkv, unsigned short* __restrict__ vpack) {
    __shared__ unsigned short tile[32][33];
    int c0 = blockIdx.x * 32;   // d-col 0..511
    int r0 = blockIdx.y * 32;   // row (b*T+t) 0..4095
    int tx = threadIdx.x, ty = threadIdx.y;
    #pragma unroll
    for (int i = 0; i < 4; i++)
        tile[ty + 8 * i][tx] =
            qkv[(size_t)(r0 + ty + 8 * i) * QKV_DIM + 2560 + c0 + tx];
    __syncthreads();
    #pragma unroll
    for (int i = 0; i < 4; i++) {
        int dcol = c0 + ty + 8 * i;
        int kv = dcol >> 7, d = dcol & 127;
        int r = r0 + tx;
        int b = r >> 11, t = r & (T_SEQ - 1);
        vpack[(size_t)((b * NKV + kv) * 64 + (t >> 5)) * 4096 +
              (d >> 4) * 512 + ((t >> 3) & 3) * 128 + (d & 15) * 8 + (t & 7)] =
            tile[tx][ty + 8 * i];
    }
}

// ---------- YaRN cos/sin table ----------
__global__ __launch_bounds__(256) void yarn_tab_kernel(float2* __restrict__ tab) {
    int idx = blockIdx.x * 256 + threadIdx.x;   // t*64 + i
    int t = idx >> 6, i = idx & 63;
    float inv = 0.25f * exp2f(-(float)i * (13.287712379549449f / 64.0f));
    float ang = (float)t * inv;
    float s, c;
    __sincosf(ang, &s, &c);
    tab[idx] = make_float2(c, s);
}

// ---------- RoPE via table ----------
__global__ __launch_bounds__(256) void rope_kernel(
        unsigned short* __restrict__ qkv, const float2* __restrict__ tab) {
    int row = blockIdx.x;
    int t = row & (T_SEQ - 1);
    const float2* tb = tab + t * 64;
    for (int p = threadIdx.x; p < 1280; p += 256) {
        int head = p >> 6, i = p & 63;
        float2 cs = tb[i];
        size_t idx = (size_t)row * QKV_DIM + head * 128 + 2 * i;
        unsigned int u = *(const unsigned int*)(qkv + idx);
        float e = bf2f((unsigned short)(u & 0xffff));
        float o = bf2f((unsigned short)(u >> 16));
        *(unsigned int*)(qkv + idx) = pkbf(e * cs.x - o * cs.y, o * cs.x + e * cs.y);
    }
}

// ---------- GEMM (m97 structure): C[M,N] = A[M,K] @ Bt[N,K]^T ----------
template <int OUT_BF16>
__global__ __launch_bounds__(256) void gemm_bt(
        const unsigned short* __restrict__ A, const unsigned short* __restrict__ Bt,
        void* __restrict__ Cout, int M, int N, int K) {
    __shared__ __align__(16) unsigned short As[128 * 32];
    __shared__ __align__(16) unsigned short Bs[128 * 32];
    int tid = threadIdx.x;
    int m0 = blockIdx.y * 128, n0 = blockIdx.x * 128;
    int wave = tid >> 6, lane = tid & 63;
    int wm = (wave & 1) * 64, wn = (wave >> 1) * 64;
    int l15 = lane & 15, quad = lane >> 4;
    int lrow = lane >> 2, lcol = (lane & 3) * 8;

    f32x4 zf = {0.f, 0.f, 0.f, 0.f};
    f32x4 acc[4][4];
    #pragma unroll
    for (int i = 0; i < 4; i++)
        #pragma unroll
        for (int j = 0; j < 4; j++) acc[i][j] = zf;

    int ca = wave * 2;
    const unsigned short* gA = A + (size_t)(m0 + ca * 16 + lrow) * K + lcol;
    const unsigned short* gB = Bt + (size_t)(n0 + ca * 16 + lrow) * K + lcol;

    for (int k0 = 0; k0 < K; k0 += 32) {
        gload_lds16(gA + k0, &As[ca * 512]);
        gload_lds16(gA + k0 + 16 * (size_t)K, &As[ca * 512 + 512]);
        gload_lds16(gB + k0, &Bs[ca * 512]);
        gload_lds16(gB + k0 + 16 * (size_t)K, &Bs[ca * 512 + 512]);
        __syncthreads();
        bf16x8 af[4], bfr[4];
        #pragma unroll
        for (int i = 0; i < 4; i++)
            af[i] = *(const bf16x8*)&As[(wm + i * 16 + l15) * 32 + quad * 8];
        #pragma unroll
        for (int i = 0; i < 4; i++)
            bfr[i] = *(const bf16x8*)&Bs[(wn + i * 16 + l15) * 32 + quad * 8];
        #pragma unroll
        for (int mi = 0; mi < 4; mi++)
            #pragma unroll
            for (int ni = 0; ni < 4; ni++)
                acc[mi][ni] = mfma16(af[mi], bfr[ni], acc[mi][ni]);
        __syncthreads();
    }
    #pragma unroll
    for (int mi = 0; mi < 4; mi++)
        #pragma unroll
        for (int ni = 0; ni < 4; ni++) {
            int row = m0 + wm + mi * 16 + quad * 4;
            int col = n0 + wn + ni * 16 + l15;
            #pragma unroll
            for (int r = 0; r < 4; r++) {
                float v = acc[mi][ni][r];
                if (OUT_BF16)
                    ((unsigned short*)Cout)[(size_t)(row + r) * N + col] = f2bf(v);
                else
                    ((float*)Cout)[(size_t)(row + r) * N + col] = v;
            }
        }
}

// ---------- flash attention ----------
// Block = 2 waves. Block owns the q-tile PAIR (j, 127-j); within each tile the
// kv-range [0,n) is split between the waves ([0,n/2) / [n/2,n)) so all 4096
// waves do ~33 steps (perfect balance, 16 busy waves/CU sustained). Partials
// combine through LDS (no running max needed: softcap bounds scores).
// K/V come from fragment-ordered packs: every load = contiguous 1 KB burst.
__device__ __forceinline__ void attn_pair(
        const unsigned short* __restrict__ qkv,
        const unsigned short* __restrict__ kpack,
        const unsigned short* __restrict__ vpack,
        unsigned short* __restrict__ attn_out,
        unsigned int* __restrict__ pT, float* __restrict__ comb,
        int b, int h, int j, int wave, int lane) {
    int l15 = lane & 15, quad = lane >> 4;
    int kv = h >> 2;
    f32x4 zf = {0.f, 0.f, 0.f, 0.f};

    const float K1 = 0.0051006972f;         // invsqrt(128)*(2/50)*log2(e)
    const float K2 = -144.26950408889634f;  // -100*log2(e)
    const float K3 = 72.13475204444817f;    // 50*log2(e)

    const unsigned short* kb_ = kpack + ((size_t)(b * NKV + kv) * 128) * 2048 + lane * 8;
    const unsigned short* vb_ = vpack + ((size_t)(b * NKV + kv) * 64) * 4096 + lane * 8;

    for (int pass = 0; pass < 2; pass++) {
        int qt = pass ? (127 - j) : j;
        int n = (qt >> 1) + 1;   // 32-key tiles in this q-tile's causal range
        int half = n >> 1;
        int lo = wave ? half : 0;
        int hi = wave ? n : half;

        // Q B-frag: Q[qrow=l15][k=c*32+quad*8+jj]
        const unsigned short* qp =
            qkv + (size_t)(b * T_SEQ + qt * 16 + l15) * QKV_DIM + h * HD + quad * 8;
        bf16x8 aq[4];
        #pragma unroll
        for (int c = 0; c < 4; c++) aq[c] = *(const bf16x8*)(qp + c * 32);

        f32x4 oacc[8];
        #pragma unroll
        for (int d = 0; d < 8; d++) oacc[d] = zf;
        float lsum = 0.f;
        int qglob = qt * 16 + l15;

        if (lo < hi) {
            bf16x8 KA[8], KB[8];
            auto loadK = [&](bf16x8* K, int t) {
                const unsigned short* a = kb_ + (size_t)t * 4096;
                #pragma unroll
                for (int c = 0; c < 4; c++) {
                    K[c]     = *(const bf16x8*)(a + c * 512);
                    K[4 + c] = *(const bf16x8*)(a + 2048 + c * 512);
                }
            };
            auto step = [&](const bf16x8* K, unsigned int* buf, int t,
                            bf16x8* Kpre, bool do_pre) {
                // V loads: 8 contiguous 1 KB bursts
                const unsigned short* v0 = vb_ + (size_t)t * 4096;
                bf16x8 Vv[8];
                #pragma unroll
                for (int dd = 0; dd < 8; dd++)
                    Vv[dd] = *(const bf16x8*)(v0 + dd * 512);
                // prefetch next K (stays in flight across PV's vmcnt wait)
                if (do_pre) loadK(Kpre, t + 1);
                // S^T = K.Q^T
                f32x4 s0 = zf, s1 = zf;
                #pragma unroll
                for (int c = 0; c < 4; c++) {
                    s0 = mfma16(K[c], aq[c], s0);
                    s1 = mfma16(K[4 + c], aq[c], s1);
                }
                bool masked = (t == n - 1);   // only the globally-last tile
                float p0[4], p1[4];
                int kb = t * 32 + quad * 4;
                #pragma unroll
                for (int r = 0; r < 4; r++) {
                    float e0 = exp2f(s0[r] * K1);
                    float e1 = exp2f(s1[r] * K1);
                    float q0 = exp2f(fmaf(K2, __builtin_amdgcn_rcpf(e0 + 1.f), K3));
                    float q1 = exp2f(fmaf(K2, __builtin_amdgcn_rcpf(e1 + 1.f), K3));
                    if (masked) {
                        q0 = (kb + r <= qglob) ? q0 : 0.f;
                        q1 = (kb + 16 + r <= qglob) ? q1 : 0.f;
                    }
                    p0[r] = q0; p1[r] = q1;
                    lsum += q0 + q1;
                }
                // P^T transpose via LDS (single wave, in-order)
                unsigned int d0 = pkbf(p0[0], p0[1]), d1 = pkbf(p0[2], p0[3]);
                unsigned int d2 = pkbf(p1[0], p1[1]), d3 = pkbf(p1[2], p1[3]);
                unsigned int* wp = buf + l15 * 20 + quad * 2;
                *(uint2*)wp = make_uint2(d0, d1);
                *(uint2*)(wp + 8) = make_uint2(d2, d3);
                __asm__ volatile("s_waitcnt lgkmcnt(0)" ::: "memory");
                bf16x8 bp = *(const bf16x8*)(buf + l15 * 20 + quad * 4);
                // O^T += V^T . P^T
                #pragma unroll
                for (int dd = 0; dd < 8; dd++) oacc[dd] = mfma16(Vv[dd], bp, oacc[dd]);
            };

            loadK(KA, lo);
            int t = lo;
            while (true) {
                bool last = (t == hi - 1);
                step(KA, pT, t, KB, !last);
                if (last) break;
                t++;
                last = (t == hi - 1);
                step(KB, pT + 320, t, KA, !last);
                if (last) break;
                t++;
            }
        }

        // combine partials across the 2 waves
        float* cl = comb + lane * 34;
        if (wave == 0) {
            #pragma unroll
            for (int dd = 0; dd < 8; dd++)
                #pragma unroll
                for (int r = 0; r < 4; r++) cl[dd * 4 + r] = oacc[dd][r];
            cl[32] = lsum;
        }
        __syncthreads();
        if (wave == 1) {
            #pragma unroll
            for (int dd = 0; dd < 8; dd++)
                #pragma unroll
                for (int r = 0; r < 4; r++) oacc[dd][r] += cl[dd * 4 + r];
            lsum += cl[32];
            float l = lsum;
            l += __shfl_xor(l, 16);
            l += __shfl_xor(l, 32);
            float rl = __builtin_amdgcn_rcpf(l);
            unsigned short* op = attn_out +
                (size_t)(b * T_SEQ + qt * 16 + l15) * C_DIM + h * HD + quad * 4;
            #pragma unroll
            for (int dd = 0; dd < 8; dd++) {
                unsigned int u0 = pkbf(oacc[dd][0] * rl, oacc[dd][1] * rl);
                unsigned int u1 = pkbf(oacc[dd][2] * rl, oacc[dd][3] * rl);
                *(uint2*)(op + dd * 16) = make_uint2(u0, u1);
            }
        }
        __syncthreads();
    }
}

// XCD-aware mapping: bid&7 = (b,kv) group, so each XCD's L2 serves ONE packed
// K/V working set (1 MB) -> L2-resident.
__global__ __launch_bounds__(128, 2) void attn_kernel(
        const unsigned short* __restrict__ qkv,
        const unsigned short* __restrict__ kpack,
        const unsigned short* __restrict__ vpack,
        unsigned short* __restrict__ attn_out) {
    __shared__ __align__(16) unsigned int pT[2][640];
    __shared__ float comb[64 * 34];
    int bid = blockIdx.x;           // 2048 = 8 groups x 256
    int g = bid & 7, i = bid >> 3;
    int b = g >> 2, kv = g & 3;
    int hh = (i >> 6) & 3, j = i & 63;
    int h = kv * 4 + hh;
    int wave = threadIdx.x >> 6, lane = threadIdx.x & 63;
    attn_pair(qkv, kpack, vpack, attn_out, pT[wave], comb, b, h, j, wave, lane);
}

extern "C" void kernel_launch(void* const* d_in, const int* in_sizes, int n_in,
                              void* d_out, int out_size, void* d_ws, size_t ws_size,
                              hipStream_t stream) {
    (void)in_sizes; (void)n_in; (void)out_size; (void)ws_size;
    const float* x = (const float*)d_in[0];
    const float* w_qkv = (const float*)d_in[1];
    const float* w_o = (const float*)d_in[2];
    char* ws = (char*)d_ws;

    unsigned short* xbf   = (unsigned short*)(ws);                       // 16 MB
    unsigned short* wqkvT = (unsigned short*)(ws + 16777216);            // 12 MB
    unsigned short* woT   = (unsigned short*)(ws + 29360128);            //  8 MB
    unsigned short* qkv   = (unsigned short*)(ws + 37748736);            // 24 MB
    unsigned short* kpack = (unsigned short*)(ws + 16777216);            // 4 MB (wqkvT dead post-gemm1)
    unsigned short* vpack = (unsigned short*)(ws + 20971520);            // 4 MB
    float2*         tab   = (float2*)(ws + 62914560);                    // 2 MB scratch tail
    unsigned short* attn  = xbf;  // xbf dead after gemm1

    cast_f32_to_bf16<<<8192, 256, 0, stream>>>(x, xbf, 2097152);
    transpose_cast_f32_bf16<<<dim3(96, 64), dim3(32, 8), 0, stream>>>(w_qkv, wqkvT, 2048, 3072);
    transpose_cast_f32_bf16<<<dim3(64, 64), dim3(32, 8), 0, stream>>>(w_o, woT, 2048, 2048);
    yarn_tab_kernel<<<512, 256, 0, stream>>>(tab);
    gemm_bt<1><<<dim3(24, 32), 256, 0, stream>>>(xbf, wqkvT, qkv, 4096, 3072, 2048);
    rope_kernel<<<4096, 256, 0, stream>>>(qkv, tab);
    pack_k<<<1024, 256, 0, stream>>>(qkv, kpack);
    pack_v<<<dim3(16, 128), dim3(32, 8), 0, stream>>>(qkv, vpack);
    attn_kernel<<<2048, 128, 0, stream>>>(qkv, kpack, vpack, attn);
    gemm_bt<0><<<dim3(16, 32), 256, 0, stream>>>(attn, woT, d_out, 4096, 2048, 2048);
}

// Round 4
// 347.879 us; speedup vs baseline: 1.6799x; 1.0078x over previous
//
#include <hip/hip_runtime.h>
#include <hip/hip_bf16.h>

// ---------- types ----------
typedef __attribute__((ext_vector_type(8))) __bf16 bf16x8;
typedef __attribute__((ext_vector_type(2))) __bf16 bf16x2;
typedef __attribute__((ext_vector_type(4))) float f32x4;

#define T_SEQ 2048
#define C_DIM 2048
#define QKV_DIM 3072
#define NKV 4
#define HD 128

#define AS1 __attribute__((address_space(1)))
#define AS3 __attribute__((address_space(3)))

__device__ __forceinline__ unsigned short f2bf(float x) {
    __hip_bfloat16 h = __float2bfloat16(x);
    return __builtin_bit_cast(unsigned short, h);
}
__device__ __forceinline__ float bf2f(unsigned short u) {
    unsigned int i = ((unsigned int)u) << 16;
    return __builtin_bit_cast(float, i);
}
__device__ __forceinline__ unsigned int pkbf(float lo, float hi) {
#if __has_builtin(__builtin_amdgcn_cvt_pk_bf16_f32)
    bf16x2 r = __builtin_amdgcn_cvt_pk_bf16_f32(lo, hi);
    return __builtin_bit_cast(unsigned int, r);
#else
    return ((unsigned int)f2bf(hi) << 16) | (unsigned int)f2bf(lo);
#endif
}
__device__ __forceinline__ f32x4 mfma16(bf16x8 a, bf16x8 b, f32x4 c) {
    return __builtin_amdgcn_mfma_f32_16x16x32_bf16(a, b, c, 0, 0, 0);
}
__device__ __forceinline__ void gload_lds16(const void* g, void* l) {
    __builtin_amdgcn_global_load_lds((const AS1 unsigned int*)g,
                                     (AS3 unsigned int*)l, 16, 0, 0);
}

// ---------- elementwise cast x -> bf16 ----------
__global__ __launch_bounds__(256) void cast_f32_to_bf16(
        const float* __restrict__ in, unsigned short* __restrict__ out, int n4) {
    int i = blockIdx.x * 256 + threadIdx.x;
    if (i >= n4) return;
    float4 v = ((const float4*)in)[i];
    uint2 o;
    o.x = pkbf(v.x, v.y);
    o.y = pkbf(v.z, v.w);
    ((uint2*)out)[i] = o;
}

// ---------- cast+transpose fp32 [rows][cols] -> bf16 [cols][rows] ----------
__global__ __launch_bounds__(256) void transpose_cast_f32_bf16(
        const float* __restrict__ in, unsigned short* __restrict__ out,
        int rows, int cols) {
    __shared__ float tile[32][33];
    int c0 = blockIdx.x * 32, r0 = blockIdx.y * 32;
    int tx = threadIdx.x, ty = threadIdx.y;
    #pragma unroll
    for (int i = 0; i < 4; i++)
        tile[ty + 8 * i][tx] = in[(size_t)(r0 + ty + 8 * i) * cols + c0 + tx];
    __syncthreads();
    #pragma unroll
    for (int i = 0; i < 4; i++)
        out[(size_t)(c0 + ty + 8 * i) * rows + r0 + tx] = f2bf(tile[tx][ty + 8 * i]);
}

// ---------- pack K (post-RoPE) into MFMA-fragment order ----------
// kpack[((b*4+kv)*128 + st)*2048 + chunk*128 + row*8 + j]
__global__ __launch_bounds__(256) void pack_k(
        const unsigned short* __restrict__ qkv, unsigned short* __restrict__ kpack) {
    int sid = blockIdx.x;                 // (b*4+kv)*128 + st, 0..1023
    int tid = threadIdx.x;
    int row = tid >> 4;                   // 0..15
    int chunk = tid & 15;                 // d-chunk of 8
    int b = sid >> 9, kv = (sid >> 7) & 3, st = sid & 127;
    int t_ = st * 16 + row;
    const unsigned short* src =
        qkv + (size_t)(b * T_SEQ + t_) * QKV_DIM + 2048 + kv * HD + chunk * 8;
    unsigned short* dst = kpack + (size_t)sid * 2048 + chunk * 128 + row * 8;
    *(uint4*)dst = *(const uint4*)src;
}

// ---------- pack V^T into MFMA-fragment order ----------
// vpack[((b*4+kv)*64 + t/32)*4096 + (d>>4)*512 + ((t>>3)&3)*128 + (d&15)*8 + (t&7)]
__global__ __launch_bounds__(256) void pack_v(
        const unsigned short* __restrict__ qkv, unsigned short* __restrict__ vpack) {
    __shared__ unsigned short tile[32][33];
    int c0 = blockIdx.x * 32;   // d-col 0..511
    int r0 = blockIdx.y * 32;   // row (b*T+t) 0..4095
    int tx = threadIdx.x, ty = threadIdx.y;
    #pragma unroll
    for (int i = 0; i < 4; i++)
        tile[ty + 8 * i][tx] =
            qkv[(size_t)(r0 + ty + 8 * i) * QKV_DIM + 2560 + c0 + tx];
    __syncthreads();
    #pragma unroll
    for (int i = 0; i < 4; i++) {
        int dcol = c0 + ty + 8 * i;
        int kv = dcol >> 7, d = dcol & 127;
        int r = r0 + tx;
        int b = r >> 11, t = r & (T_SEQ - 1);
        vpack[(size_t)((b * NKV + kv) * 64 + (t >> 5)) * 4096 +
              (d >> 4) * 512 + ((t >> 3) & 3) * 128 + (d & 15) * 8 + (t & 7)] =
            tile[tx][ty + 8 * i];
    }
}

// ---------- YaRN cos/sin table ----------
__global__ __launch_bounds__(256) void yarn_tab_kernel(float2* __restrict__ tab) {
    int idx = blockIdx.x * 256 + threadIdx.x;   // t*64 + i
    int t = idx >> 6, i = idx & 63;
    float inv = 0.25f * exp2f(-(float)i * (13.287712379549449f / 64.0f));
    float ang = (float)t * inv;
    float s, c;
    __sincosf(ang, &s, &c);
    tab[idx] = make_float2(c, s);
}

// ---------- RoPE via table ----------
__global__ __launch_bounds__(256) void rope_kernel(
        unsigned short* __restrict__ qkv, const float2* __restrict__ tab) {
    int row = blockIdx.x;
    int t = row & (T_SEQ - 1);
    const float2* tb = tab + t * 64;
    for (int p = threadIdx.x; p < 1280; p += 256) {
        int head = p >> 6, i = p & 63;
        float2 cs = tb[i];
        size_t idx = (size_t)row * QKV_DIM + head * 128 + 2 * i;
        unsigned int u = *(const unsigned int*)(qkv + idx);
        float e = bf2f((unsigned short)(u & 0xffff));
        float o = bf2f((unsigned short)(u >> 16));
        *(unsigned int*)(qkv + idx) = pkbf(e * cs.x - o * cs.y, o * cs.x + e * cs.y);
    }
}

// ---------- GEMM (m97 structure): C[M,N] = A[M,K] @ Bt[N,K]^T ----------
template <int OUT_BF16>
__global__ __launch_bounds__(256) void gemm_bt(
        const unsigned short* __restrict__ A, const unsigned short* __restrict__ Bt,
        void* __restrict__ Cout, int M, int N, int K) {
    __shared__ __align__(16) unsigned short As[128 * 32];
    __shared__ __align__(16) unsigned short Bs[128 * 32];
    int tid = threadIdx.x;
    int m0 = blockIdx.y * 128, n0 = blockIdx.x * 128;
    int wave = tid >> 6, lane = tid & 63;
    int wm = (wave & 1) * 64, wn = (wave >> 1) * 64;
    int l15 = lane & 15, quad = lane >> 4;
    int lrow = lane >> 2, lcol = (lane & 3) * 8;

    f32x4 zf = {0.f, 0.f, 0.f, 0.f};
    f32x4 acc[4][4];
    #pragma unroll
    for (int i = 0; i < 4; i++)
        #pragma unroll
        for (int j = 0; j < 4; j++) acc[i][j] = zf;

    int ca = wave * 2;
    const unsigned short* gA = A + (size_t)(m0 + ca * 16 + lrow) * K + lcol;
    const unsigned short* gB = Bt + (size_t)(n0 + ca * 16 + lrow) * K + lcol;

    for (int k0 = 0; k0 < K; k0 += 32) {
        gload_lds16(gA + k0, &As[ca * 512]);
        gload_lds16(gA + k0 + 16 * (size_t)K, &As[ca * 512 + 512]);
        gload_lds16(gB + k0, &Bs[ca * 512]);
        gload_lds16(gB + k0 + 16 * (size_t)K, &Bs[ca * 512 + 512]);
        __syncthreads();
        bf16x8 af[4], bfr[4];
        #pragma unroll
        for (int i = 0; i < 4; i++)
            af[i] = *(const bf16x8*)&As[(wm + i * 16 + l15) * 32 + quad * 8];
        #pragma unroll
        for (int i = 0; i < 4; i++)
            bfr[i] = *(const bf16x8*)&Bs[(wn + i * 16 + l15) * 32 + quad * 8];
        #pragma unroll
        for (int mi = 0; mi < 4; mi++)
            #pragma unroll
            for (int ni = 0; ni < 4; ni++)
                acc[mi][ni] = mfma16(af[mi], bfr[ni], acc[mi][ni]);
        __syncthreads();
    }
    #pragma unroll
    for (int mi = 0; mi < 4; mi++)
        #pragma unroll
        for (int ni = 0; ni < 4; ni++) {
            int row = m0 + wm + mi * 16 + quad * 4;
            int col = n0 + wn + ni * 16 + l15;
            #pragma unroll
            for (int r = 0; r < 4; r++) {
                float v = acc[mi][ni][r];
                if (OUT_BF16)
                    ((unsigned short*)Cout)[(size_t)(row + r) * N + col] = f2bf(v);
                else
                    ((float*)Cout)[(size_t)(row + r) * N + col] = v;
            }
        }
}

// ---------- flash attention ----------
// GQA head-sharing: 4 heads share each kv-group's K/V. Each wave processes
// TWO heads (hA, hB=hA+1) of the same kv-group for its q-tile: one K/V load
// feeds two independent QK->softmax->PV chains (2x ILP, half the VMEM per
// FLOP). Block = 2 waves; block owns the q-tile PAIR (j, 127-j); each tile's
// kv-range is split between the waves (perfect ~33-step balance). Epilogue:
// wave0 combines+writes head A, wave1 head B (cross-partials through LDS;
// plain addition is enough: softcap bounds scores, no running max needed).
__device__ __forceinline__ void attn_pair(
        const unsigned short* __restrict__ qkv,
        const unsigned short* __restrict__ kpack,
        const unsigned short* __restrict__ vpack,
        unsigned short* __restrict__ attn_out,
        unsigned int* __restrict__ pT, float* __restrict__ comb,
        int b, int hA, int j, int wave, int lane) {
    int l15 = lane & 15, quad = lane >> 4;
    int kv = hA >> 2;
    f32x4 zf = {0.f, 0.f, 0.f, 0.f};

    const float K1 = 0.0051006972f;         // invsqrt(128)*(2/50)*log2(e)
    const float K2 = -144.26950408889634f;  // -100*log2(e)
    const float K3 = 72.13475204444817f;    // 50*log2(e)

    const unsigned short* kb_ = kpack + ((size_t)(b * NKV + kv) * 128) * 2048 + lane * 8;
    const unsigned short* vb_ = vpack + ((size_t)(b * NKV + kv) * 64) * 4096 + lane * 8;

    // comb layout: [wave][lane][34]: own partials of the OTHER wave's head
    float* myStore = comb + (wave * 64 + lane) * 34;
    float* peer    = comb + ((1 - wave) * 64 + lane) * 34;

    for (int pass = 0; pass < 2; pass++) {
        int qt = pass ? (127 - j) : j;
        int n = (qt >> 1) + 1;   // 32-key tiles in this q-tile's causal range
        int half = n >> 1;
        int lo = wave ? half : 0;
        int hi = wave ? n : half;

        // Q B-frags for both heads: Q[qrow=l15][k=c*32+quad*8+jj]
        const unsigned short* qp =
            qkv + (size_t)(b * T_SEQ + qt * 16 + l15) * QKV_DIM + hA * HD + quad * 8;
        bf16x8 aqA[4], aqB[4];
        #pragma unroll
        for (int c = 0; c < 4; c++) {
            aqA[c] = *(const bf16x8*)(qp + c * 32);
            aqB[c] = *(const bf16x8*)(qp + HD + c * 32);
        }

        f32x4 oA[8], oB[8];
        #pragma unroll
        for (int d = 0; d < 8; d++) { oA[d] = zf; oB[d] = zf; }
        float lsA = 0.f, lsB = 0.f;
        int qglob = qt * 16 + l15;

        if (lo < hi) {
            bf16x8 KA[8], KB[8];
            auto loadK = [&](bf16x8* K, int t) {
                const unsigned short* a = kb_ + (size_t)t * 4096;
                #pragma unroll
                for (int c = 0; c < 4; c++) {
                    K[c]     = *(const bf16x8*)(a + c * 512);
                    K[4 + c] = *(const bf16x8*)(a + 2048 + c * 512);
                }
            };
            auto step = [&](const bf16x8* K, unsigned int* buf, int t,
                            bf16x8* Kpre, bool do_pre) {
                // V loads: 8 contiguous 1 KB bursts (shared by both heads)
                const unsigned short* v0 = vb_ + (size_t)t * 4096;
                bf16x8 Vv[8];
                #pragma unroll
                for (int dd = 0; dd < 8; dd++)
                    Vv[dd] = *(const bf16x8*)(v0 + dd * 512);
                // prefetch next K (stays in flight across PV's vmcnt wait)
                if (do_pre) loadK(Kpre, t + 1);
                // S^T = K.Q^T for both heads (independent chains)
                f32x4 s0A = zf, s1A = zf, s0B = zf, s1B = zf;
                #pragma unroll
                for (int c = 0; c < 4; c++) {
                    s0A = mfma16(K[c],     aqA[c], s0A);
                    s1A = mfma16(K[4 + c], aqA[c], s1A);
                    s0B = mfma16(K[c],     aqB[c], s0B);
                    s1B = mfma16(K[4 + c], aqB[c], s1B);
                }
                bool masked = (t == n - 1);   // only the globally-last tile
                float p0A[4], p1A[4], p0B[4], p1B[4];
                int kb = t * 32 + quad * 4;
                #pragma unroll
                for (int r = 0; r < 4; r++) {
                    float e0A = exp2f(s0A[r] * K1), e1A = exp2f(s1A[r] * K1);
                    float e0B = exp2f(s0B[r] * K1), e1B = exp2f(s1B[r] * K1);
                    float q0A = exp2f(fmaf(K2, __builtin_amdgcn_rcpf(e0A + 1.f), K3));
                    float q1A = exp2f(fmaf(K2, __builtin_amdgcn_rcpf(e1A + 1.f), K3));
                    float q0B = exp2f(fmaf(K2, __builtin_amdgcn_rcpf(e0B + 1.f), K3));
                    float q1B = exp2f(fmaf(K2, __builtin_amdgcn_rcpf(e1B + 1.f), K3));
                    if (masked) {
                        bool m0 = (kb + r <= qglob), m1 = (kb + 16 + r <= qglob);
                        q0A = m0 ? q0A : 0.f;  q1A = m1 ? q1A : 0.f;
                        q0B = m0 ? q0B : 0.f;  q1B = m1 ? q1B : 0.f;
                    }
                    p0A[r] = q0A; p1A[r] = q1A; lsA += q0A + q1A;
                    p0B[r] = q0B; p1B[r] = q1B; lsB += q0B + q1B;
                }
                // P^T transpose via LDS, both heads, single wait
                unsigned int* wpA = buf + l15 * 20 + quad * 2;
                unsigned int* wpB = wpA + 320;
                *(uint2*)wpA       = make_uint2(pkbf(p0A[0], p0A[1]), pkbf(p0A[2], p0A[3]));
                *(uint2*)(wpA + 8) = make_uint2(pkbf(p1A[0], p1A[1]), pkbf(p1A[2], p1A[3]));
                *(uint2*)wpB       = make_uint2(pkbf(p0B[0], p0B[1]), pkbf(p0B[2], p0B[3]));
                *(uint2*)(wpB + 8) = make_uint2(pkbf(p1B[0], p1B[1]), pkbf(p1B[2], p1B[3]));
                __asm__ volatile("s_waitcnt lgkmcnt(0)" ::: "memory");
                bf16x8 bpA = *(const bf16x8*)(buf + l15 * 20 + quad * 4);
                bf16x8 bpB = *(const bf16x8*)(buf + 320 + l15 * 20 + quad * 4);
                // O^T += V^T . P^T (both heads, shared V)
                #pragma unroll
                for (int dd = 0; dd < 8; dd++) {
                    oA[dd] = mfma16(Vv[dd], bpA, oA[dd]);
                    oB[dd] = mfma16(Vv[dd], bpB, oB[dd]);
                }
            };

            loadK(KA, lo);
            int t = lo;
            while (true) {
                bool last = (t == hi - 1);
                step(KA, pT, t, KB, !last);
                if (last) break;
                t++;
                last = (t == hi - 1);
                step(KB, pT + 640, t, KA, !last);
                if (last) break;
                t++;
            }
        }

        // exchange: each wave stores the partials of the head the OTHER wave
        // will write. wave0 writes head A -> stores its B-partials; wave1
        // writes head B -> stores its A-partials.
        {
            f32x4* po = wave ? oA : oB;
            float pls = wave ? lsA : lsB;
            #pragma unroll
            for (int dd = 0; dd < 8; dd++)
                #pragma unroll
                for (int r = 0; r < 4; r++) myStore[dd * 4 + r] = po[dd][r];
            myStore[32] = pls;
        }
        __syncthreads();
        {
            f32x4* mo = wave ? oB : oA;
            float mls = wave ? lsB : lsA;
            #pragma unroll
            for (int dd = 0; dd < 8; dd++)
                #pragma unroll
                for (int r = 0; r < 4; r++) mo[dd][r] += peer[dd * 4 + r];
            mls += peer[32];
            float l = mls;
            l += __shfl_xor(l, 16);
            l += __shfl_xor(l, 32);
            float rl = __builtin_amdgcn_rcpf(l);
            int h = hA + wave;
            unsigned short* op = attn_out +
                (size_t)(b * T_SEQ + qt * 16 + l15) * C_DIM + h * HD + quad * 4;
            #pragma unroll
            for (int dd = 0; dd < 8; dd++) {
                unsigned int u0 = pkbf(mo[dd][0] * rl, mo[dd][1] * rl);
                unsigned int u1 = pkbf(mo[dd][2] * rl, mo[dd][3] * rl);
                *(uint2*)(op + dd * 16) = make_uint2(u0, u1);
            }
        }
        __syncthreads();
    }
}

// 1024 blocks = (b,kv) 8 x (head-pair 2 x j 64). bid&7 = (b,kv) group keeps
// each XCD's L2 serving one packed K/V working set.
__global__ __launch_bounds__(128) void attn_kernel(
        const unsigned short* __restrict__ qkv,
        const unsigned short* __restrict__ kpack,
        const unsigned short* __restrict__ vpack,
        unsigned short* __restrict__ attn_out) {
    __shared__ __align__(16) unsigned int pT[2][1280];
    __shared__ float comb[2 * 64 * 34];
    int bid = blockIdx.x;           // 1024 = 8 groups x 128
    int g = bid & 7, i = bid >> 3;
    int b = g >> 2, kv = g & 3;
    int hp = (i >> 6) & 1, j = i & 63;
    int hA = kv * 4 + hp * 2;
    int wave = threadIdx.x >> 6, lane = threadIdx.x & 63;
    attn_pair(qkv, kpack, vpack, attn_out, pT[wave], comb, b, hA, j, wave, lane);
}

extern "C" void kernel_launch(void* const* d_in, const int* in_sizes, int n_in,
                              void* d_out, int out_size, void* d_ws, size_t ws_size,
                              hipStream_t stream) {
    (void)in_sizes; (void)n_in; (void)out_size; (void)ws_size;
    const float* x = (const float*)d_in[0];
    const float* w_qkv = (const float*)d_in[1];
    const float* w_o = (const float*)d_in[2];
    char* ws = (char*)d_ws;

    unsigned short* xbf   = (unsigned short*)(ws);                       // 16 MB
    unsigned short* wqkvT = (unsigned short*)(ws + 16777216);            // 12 MB
    unsigned short* woT   = (unsigned short*)(ws + 29360128);            //  8 MB
    unsigned short* qkv   = (unsigned short*)(ws + 37748736);            // 24 MB
    unsigned short* kpack = (unsigned short*)(ws + 16777216);            // 4 MB (wqkvT dead post-gemm1)
    unsigned short* vpack = (unsigned short*)(ws + 20971520);            // 4 MB
    float2*         tab   = (float2*)(ws + 62914560);                    // 2 MB scratch tail
    unsigned short* attn  = xbf;  // xbf dead after gemm1

    cast_f32_to_bf16<<<8192, 256, 0, stream>>>(x, xbf, 2097152);
    transpose_cast_f32_bf16<<<dim3(96, 64), dim3(32, 8), 0, stream>>>(w_qkv, wqkvT, 2048, 3072);
    transpose_cast_f32_bf16<<<dim3(64, 64), dim3(32, 8), 0, stream>>>(w_o, woT, 2048, 2048);
    yarn_tab_kernel<<<512, 256, 0, stream>>>(tab);
    gemm_bt<1><<<dim3(24, 32), 256, 0, stream>>>(xbf, wqkvT, qkv, 4096, 3072, 2048);
    rope_kernel<<<4096, 256, 0, stream>>>(qkv, tab);
    pack_k<<<1024, 256, 0, stream>>>(qkv, kpack);
    pack_v<<<dim3(16, 128), dim3(32, 8), 0, stream>>>(qkv, vpack);
    attn_kernel<<<1024, 128, 0, stream>>>(qkv, kpack, vpack, attn);
    gemm_bt<0><<<dim3(16, 32), 256, 0, stream>>>(attn, woT, d_out, 4096, 2048, 2048);
}